// Round 3
// baseline (524.123 us; speedup 1.0000x reference)
//
#include <hip/hip_runtime.h>
#include <hip/hip_bf16.h>

#define HID 128
#define INP 64
#define SPANN 8
#define NOUT 2
#define DAYS 20
#define RT 4                 // 16-row tiles per block
#define ROWS (16*RT)         // 64 batch rows per block
#define NTH 512              // 8 waves

typedef __attribute__((ext_vector_type(8))) short short8;
typedef __attribute__((ext_vector_type(4))) float f32x4;
typedef __attribute__((ext_vector_type(2))) float f32x2;
typedef unsigned int u32;
typedef __attribute__((ext_vector_type(2))) u32 u32x2;
typedef unsigned short u16;

#define MFMA(a,b,c) __builtin_amdgcn_mfma_f32_16x16x32_bf16(a,b,c,0,0,0)
#define RCPF(x)  __builtin_amdgcn_rcpf(x)
#define EXP2F(x) __builtin_amdgcn_exp2f(x)
#define LOG2E  1.4426950408889634f
#define LOG2E2 2.8853900817779268f

// HW bf16 pack (compiler emits v_cvt_pk_bf16_f32 from scalar-cast pairs; m240)
__device__ __forceinline__ u32 pack2(float a, float b){
    __hip_bfloat162 h = __float22bfloat162_rn(float2{a, b});
    u32 r; __builtin_memcpy(&r, &h, 4); return r;
}
__device__ __forceinline__ float sigf(float x){            // 1/(1+e^-x), rcp ~1ulp
    return RCPF(1.0f + EXP2F(-LOG2E * x));
}
__device__ __forceinline__ float tanhf_(float x){          // 1 - 2/(1+e^(2x))
    return fmaf(-2.0f, RCPF(1.0f + EXP2F(LOG2E2 * x)), 1.0f);
}

union frag_u { short8 s; u32 w[4]; };
// load 8 consecutive f32 and convert to a bf16 MFMA fragment (4 VGPRs)
__device__ __forceinline__ short8 ldfrag(const float* p){
    const f32x4 a = *(const f32x4*)p;
    const f32x4 b = *(const f32x4*)(p+4);
    frag_u f;
    f.w[0] = pack2(a[0],a[1]); f.w[1] = pack2(a[2],a[3]);
    f.w[2] = pack2(b[0],b[1]); f.w[3] = pack2(b[2],b[3]);
    return f.s;
}

// Fragment conventions (16x16x32 bf16):
//  A: lane holds A[m = l&15][k = (l>>4)*8 + j]   (weights, rows = gate cols)
//  B: lane holds B[k = (l>>4)*8 + j][n = l&15]   (h^T / x^T, n = batch row)
//  D: lane holds D[m = (l>>4)*4 + q][n = l&15]   (m89-verified)
// h/x LDS are fragment-major: for k-step ks, lane l reads 16B at ks*1024 + l*16.

__global__ __launch_bounds__(NTH, 4) void gru_mfma(
    const float* __restrict__ hx, const float* __restrict__ w_ih,
    const float* __restrict__ w_hh, const float* __restrict__ b_ih,
    const float* __restrict__ b_hh, const float* __restrict__ fc_in_w,
    const float* __restrict__ fc_in_b, const float* __restrict__ fc_out_w,
    const float* __restrict__ fc_out_b, const float* __restrict__ span_w,
    const float* __restrict__ span_b, float* __restrict__ out, int bs)
{
    __shared__ u16 hL[2][RT*2048];   // 2 x 4 tiles x (16 rows x 128 cols) bf16 = 32 KiB
    __shared__ u16 xL[2][RT*1024];   // 2 x 4 tiles x (16 rows x  64 cols) bf16 = 16 KiB

    const int tid = threadIdx.x;
    const int wid = tid >> 6;        // 0..7, owns gate tiles {wid, wid+8, wid+16}
    const int l   = tid & 63;
    const int r15 = l & 15;          // batch row within tile (B-frag col / D col)
    const int hi  = l >> 4;          // lane k-group / D row-group
    const int row0 = blockIdx.x * ROWS;

    // ---- weight fragments, cached in VGPRs for the whole kernel ----
    short8 whhR[4], whhZ[4], whhN[4];
    short8 wihR[2], wihZ[2], wihN[2];
    short8 fwA[4];                   // fc_in (wid<4) or fc_out (wid==4)
    const int g0 = wid*16 + r15;     // this lane's gate row (R section)
    #pragma unroll
    for (int ks = 0; ks < 4; ++ks){
        whhR[ks] = ldfrag(w_hh + (size_t)(      g0)*HID + ks*32 + hi*8);
        whhZ[ks] = ldfrag(w_hh + (size_t)(128 + g0)*HID + ks*32 + hi*8);
        whhN[ks] = ldfrag(w_hh + (size_t)(256 + g0)*HID + ks*32 + hi*8);
    }
    #pragma unroll
    for (int ks = 0; ks < 2; ++ks){
        wihR[ks] = ldfrag(w_ih + (size_t)(      g0)*INP + ks*32 + hi*8);
        wihZ[ks] = ldfrag(w_ih + (size_t)(128 + g0)*INP + ks*32 + hi*8);
        wihN[ks] = ldfrag(w_ih + (size_t)(256 + g0)*INP + ks*32 + hi*8);
    }
    {
        const short8 zz = {0,0,0,0,0,0,0,0};
        #pragma unroll
        for (int ks = 0; ks < 4; ++ks){
            if (wid < 4)            fwA[ks] = ldfrag(fc_in_w + (size_t)(wid*16 + r15)*HID + ks*32 + hi*8);
            else if (wid == 4)      fwA[ks] = (r15 < NOUT) ? ldfrag(fc_out_w + (size_t)r15*HID + ks*32 + hi*8) : zz;
            else                    fwA[ks] = zz;
        }
    }

    // ---- per-thread bias vectors, used directly as MFMA C-init ----
    f32x4 bRv, bZv, bNiv, bNhv, fbv;
    #pragma unroll
    for (int q = 0; q < 4; ++q){
        const int g = wid*16 + hi*4 + q;
        bRv[q]  = b_ih[g]       + b_hh[g];
        bZv[q]  = b_ih[128 + g] + b_hh[128 + g];
        bNiv[q] = b_ih[256 + g];
        bNhv[q] = b_hh[256 + g];
        if (wid < 4)       fbv[q] = fc_in_b[wid*16 + hi*4 + q];
        else if (wid == 4) fbv[q] = (hi == 0 && q < NOUT) ? fc_out_b[q] : 0.0f;
        else               fbv[q] = 0.0f;
    }

    // writer u32 index inside a 2048-u16 h tile (fragment-major scatter):
    //  c = wid*16 + hi*4 + q ; ks'=c>>5, kg=(c>>3)&3, j=c&7 -> pairs (q01) are u32-adjacent
    const int wu32 = (wid>>1)*256 + (((wid&1)*2 + (hi>>1))*16 + r15)*4 + (hi&1)*2;

    // ---- h_old f32 registers + fill h buffer 0 + zero x buffer 0 ----
    float hOld[RT][4];
    const int c0 = wid*16 + hi*4;
    #pragma unroll
    for (int rt = 0; rt < RT; ++rt){
        const f32x4 h4 = *(const f32x4*)(hx + (size_t)(row0 + rt*16 + r15)*HID + c0);
        #pragma unroll
        for (int q = 0; q < 4; ++q) hOld[rt][q] = h4[q];
        u32x2 wv; wv[0] = pack2(h4[0], h4[1]); wv[1] = pack2(h4[2], h4[3]);
        *(u32x2*)((u32*)&hL[0][rt*2048] + wu32) = wv;
    }
    {
        u32* xb = (u32*)&xL[0][0];
        for (int i = tid; i < RT*512; i += NTH) xb[i] = 0u;   // x0 = zeros
    }
    __syncthreads();

    // ---- span head (wave 5): softmax(hx @ span_w.T + b), from day-0 h buffer ----
    if (wid == 5){
        const short8 zz = {0,0,0,0,0,0,0,0};
        short8 spw[4];
        #pragma unroll
        for (int ks = 0; ks < 4; ++ks)
            spw[ks] = (r15 < SPANN) ? ldfrag(span_w + (size_t)r15*HID + ks*32 + hi*8) : zz;
        f32x4 sb = {0.0f, 0.0f, 0.0f, 0.0f};
        #pragma unroll
        for (int q = 0; q < 4; ++q) if (hi < 2) sb[q] = span_b[hi*4 + q];
        #pragma unroll
        for (int rt = 0; rt < RT; ++rt){
            const short8* hf = (const short8*)&hL[0][rt*2048];
            f32x4 acc = sb;
            #pragma unroll
            for (int ks = 0; ks < 4; ++ks) acc = MFMA(spw[ks], hf[ks*64 + l], acc);
            if (hi < 2){   // lanes 0..31 hold spans hi*4+q for row r15
                float m = fmaxf(fmaxf(acc[0], acc[1]), fmaxf(acc[2], acc[3]));
                m = fmaxf(m, __shfl_xor(m, 16));
                float e0 = EXP2F(LOG2E*(acc[0]-m)), e1 = EXP2F(LOG2E*(acc[1]-m));
                float e2 = EXP2F(LOG2E*(acc[2]-m)), e3 = EXP2F(LOG2E*(acc[3]-m));
                float s = e0 + e1 + e2 + e3;
                s += __shfl_xor(s, 16);
                const float inv = RCPF(s);
                f32x4 o = {e0*inv, e1*inv, e2*inv, e3*inv};
                *(f32x4*)(out + (size_t)(row0 + rt*16 + r15)*SPANN + hi*4) = o;
            }
        }
    }

    float* __restrict__ outp = out + (size_t)bs * SPANN;

    #pragma unroll 2
    for (int day = 0; day < DAYS; ++day){
        const int p = day & 1;
        const u16* hRd = hL[p];
        const u16* xRd = xL[p];
        u32* hWr = (u32*)hL[p^1];
        u32* xWr = (u32*)xL[p^1];

        // ============ Phase A: gates + h update (all 8 waves) ============
        #pragma unroll
        for (int rt = 0; rt < RT; ++rt){
            const short8* hf = (const short8*)(hRd + rt*2048);
            const short8* xf = (const short8*)(xRd + rt*1024);
            const short8 h0 = hf[l], h1 = hf[64+l], h2 = hf[128+l], h3 = hf[192+l];
            const short8 x0 = xf[l], x1 = xf[64+l];

            f32x4 aR  = MFMA(whhR[0], h0, bRv);
            f32x4 aZ  = MFMA(whhZ[0], h0, bZv);
            f32x4 aNh = MFMA(whhN[0], h0, bNhv);
            aR  = MFMA(whhR[1], h1, aR);  aZ  = MFMA(whhZ[1], h1, aZ);  aNh = MFMA(whhN[1], h1, aNh);
            aR  = MFMA(whhR[2], h2, aR);  aZ  = MFMA(whhZ[2], h2, aZ);  aNh = MFMA(whhN[2], h2, aNh);
            aR  = MFMA(whhR[3], h3, aR);  aZ  = MFMA(whhZ[3], h3, aZ);  aNh = MFMA(whhN[3], h3, aNh);
            f32x4 aNi = MFMA(wihN[0], x0, bNiv);
            aR  = MFMA(wihR[0], x0, aR);  aZ  = MFMA(wihZ[0], x0, aZ);
            aNi = MFMA(wihN[1], x1, aNi);
            aR  = MFMA(wihR[1], x1, aR);  aZ  = MFMA(wihZ[1], x1, aZ);

            float hn[4];
            #pragma unroll
            for (int q = 0; q < 4; ++q){
                const float rg = sigf(aR[q]);
                const float zg = sigf(aZ[q]);
                const float nn = tanhf_(fmaf(rg, aNh[q], aNi[q]));
                hn[q] = fmaf(zg, hOld[rt][q] - nn, nn);
                hOld[rt][q] = hn[q];
            }
            u32x2 wv; wv[0] = pack2(hn[0], hn[1]); wv[1] = pack2(hn[2], hn[3]);
            *(u32x2*)(hWr + rt*1024 + wu32) = wv;
        }
        __syncthreads();

        // ============ Phase B: fc_in (waves 0-3), fc_out+softmax (wave 4) ============
        if (wid < 4){
            #pragma unroll
            for (int rt = 0; rt < RT; ++rt){
                const short8* hf = (const short8*)(hL[p^1] + rt*2048);
                const short8 h0 = hf[l], h1 = hf[64+l], h2 = hf[128+l], h3 = hf[192+l];
                f32x4 ax = MFMA(fwA[0], h0, fbv);
                ax = MFMA(fwA[1], h1, ax);
                ax = MFMA(fwA[2], h2, ax);
                ax = MFMA(fwA[3], h3, ax);
                u32x2 wv;
                wv[0] = pack2(fmaxf(ax[0],0.0f), fmaxf(ax[1],0.0f));
                wv[1] = pack2(fmaxf(ax[2],0.0f), fmaxf(ax[3],0.0f));
                *(u32x2*)(xWr + rt*512 + wu32) = wv;
            }
        } else if (wid == 4){
            #pragma unroll
            for (int rt = 0; rt < RT; ++rt){
                const short8* hf = (const short8*)(hL[p^1] + rt*2048);
                const short8 h0 = hf[l], h1 = hf[64+l], h2 = hf[128+l], h3 = hf[192+l];
                f32x4 ao = MFMA(fwA[0], h0, fbv);
                ao = MFMA(fwA[1], h1, ao);
                ao = MFMA(fwA[2], h2, ao);
                ao = MFMA(fwA[3], h3, ao);
                if (hi == 0){   // lanes 0..15 hold both logits (q=0,1) for row r15
                    const float m  = fmaxf(ao[0], ao[1]);
                    const float e0 = EXP2F(LOG2E*(ao[0]-m));
                    const float e1 = EXP2F(LOG2E*(ao[1]-m));
                    const float inv = RCPF(e0 + e1);
                    f32x2 o = {e0*inv, e1*inv};
                    *(f32x2*)(outp + ((size_t)(row0 + rt*16 + r15)*DAYS + day)*NOUT) = o;
                }
            }
        }
        __syncthreads();
    }
}

extern "C" void kernel_launch(void* const* d_in, const int* in_sizes, int n_in,
                              void* d_out, int out_size, void* d_ws, size_t ws_size,
                              hipStream_t stream) {
    const float* hx       = (const float*)d_in[0];
    const float* w_ih     = (const float*)d_in[1];
    const float* w_hh     = (const float*)d_in[2];
    const float* b_ih     = (const float*)d_in[3];
    const float* b_hh     = (const float*)d_in[4];
    const float* fc_in_w  = (const float*)d_in[5];
    const float* fc_in_b  = (const float*)d_in[6];
    const float* fc_out_w = (const float*)d_in[7];
    const float* fc_out_b = (const float*)d_in[8];
    const float* span_w   = (const float*)d_in[9];
    const float* span_b   = (const float*)d_in[10];
    float* out = (float*)d_out;

    const int bs = in_sizes[0] / HID;            // 32768
    dim3 grid(bs / ROWS), block(NTH);
    gru_mfma<<<grid, block, 0, stream>>>(hx, w_ih, w_hh, b_ih, b_hh,
                                         fc_in_w, fc_in_b, fc_out_w, fc_out_b,
                                         span_w, span_b, out, bs);
}

// Round 4
// 149.704 us; speedup vs baseline: 3.5011x; 3.5011x over previous
//
#include <hip/hip_runtime.h>
#include <hip/hip_bf16.h>

#define HID 128
#define INP 64
#define SPANN 8
#define NOUT 2
#define DAYS 20
#define RT 4                 // 16-row tiles per block
#define ROWS (16*RT)         // 64 batch rows per block
#define NTH 512              // 8 waves

typedef __attribute__((ext_vector_type(8))) short short8;
typedef __attribute__((ext_vector_type(4))) float f32x4;
typedef __attribute__((ext_vector_type(2))) float f32x2;
typedef unsigned int u32;
typedef __attribute__((ext_vector_type(2))) u32 u32x2;
typedef unsigned short u16;

#define MFMA(a,b,c) __builtin_amdgcn_mfma_f32_16x16x32_bf16(a,b,c,0,0,0)
#define RCPF(x)  __builtin_amdgcn_rcpf(x)
#define EXP2F(x) __builtin_amdgcn_exp2f(x)
#define LOG2E  1.4426950408889634f
#define LOG2E2 2.8853900817779268f

// HW bf16 pack (compiler emits v_cvt_pk_bf16_f32 from scalar-cast pairs; m240)
__device__ __forceinline__ u32 pack2(float a, float b){
    __hip_bfloat162 h = __float22bfloat162_rn(float2{a, b});
    u32 r; __builtin_memcpy(&r, &h, 4); return r;
}
__device__ __forceinline__ float sigf(float x){            // 1/(1+e^-x), rcp ~1ulp
    return RCPF(1.0f + EXP2F(-LOG2E * x));
}
__device__ __forceinline__ float tanhf_(float x){          // 1 - 2/(1+e^(2x))
    return fmaf(-2.0f, RCPF(1.0f + EXP2F(LOG2E2 * x)), 1.0f);
}

union frag_u { short8 s; u32 w[4]; };
// load 8 consecutive f32 and convert to a bf16 MFMA fragment (4 VGPRs)
__device__ __forceinline__ short8 ldfrag(const float* p){
    const f32x4 a = *(const f32x4*)p;
    const f32x4 b = *(const f32x4*)(p+4);
    frag_u f;
    f.w[0] = pack2(a[0],a[1]); f.w[1] = pack2(a[2],a[3]);
    f.w[2] = pack2(b[0],b[1]); f.w[3] = pack2(b[2],b[3]);
    return f.s;
}

// Fragment conventions (16x16x32 bf16):
//  A: lane holds A[m = l&15][k = (l>>4)*8 + j]   (weights, rows = gate cols)
//  B: lane holds B[k = (l>>4)*8 + j][n = l&15]   (h^T / x^T, n = batch row)
//  D: lane holds D[m = (l>>4)*4 + q][n = l&15]   (m89-verified)
// h/x LDS are fragment-major: for k-step ks, lane l reads 16B at ks*1024 + l*16.

// NOTE: min-waves/EU=2 (NOT 4): VGPR cap 256 -> the ~88 resident weight-frag
// VGPRs fit (R2: 128 VGPR, zero spill). =4 capped at 128 and spilled the
// weight set to scratch -> 1.35 GB/launch HBM traffic, 2.4x slower (R3).
__global__ __launch_bounds__(NTH, 2) void gru_mfma(
    const float* __restrict__ hx, const float* __restrict__ w_ih,
    const float* __restrict__ w_hh, const float* __restrict__ b_ih,
    const float* __restrict__ b_hh, const float* __restrict__ fc_in_w,
    const float* __restrict__ fc_in_b, const float* __restrict__ fc_out_w,
    const float* __restrict__ fc_out_b, const float* __restrict__ span_w,
    const float* __restrict__ span_b, float* __restrict__ out, int bs)
{
    __shared__ u16 hL[2][RT*2048];   // 2 x 4 tiles x (16 rows x 128 cols) bf16 = 32 KiB
    __shared__ u16 xL[2][RT*1024];   // 2 x 4 tiles x (16 rows x  64 cols) bf16 = 16 KiB

    const int tid = threadIdx.x;
    const int wid = tid >> 6;        // 0..7, owns gate tiles {wid, wid+8, wid+16}
    const int l   = tid & 63;
    const int r15 = l & 15;          // batch row within tile (B-frag col / D col)
    const int hi  = l >> 4;          // lane k-group / D row-group
    const int row0 = blockIdx.x * ROWS;

    // ---- weight fragments, cached in VGPRs for the whole kernel ----
    short8 whhR[4], whhZ[4], whhN[4];
    short8 wihR[2], wihZ[2], wihN[2];
    short8 fwA[4];                   // fc_in (wid<4) or fc_out (wid==4)
    const int g0 = wid*16 + r15;     // this lane's gate row (R section)
    #pragma unroll
    for (int ks = 0; ks < 4; ++ks){
        whhR[ks] = ldfrag(w_hh + (size_t)(      g0)*HID + ks*32 + hi*8);
        whhZ[ks] = ldfrag(w_hh + (size_t)(128 + g0)*HID + ks*32 + hi*8);
        whhN[ks] = ldfrag(w_hh + (size_t)(256 + g0)*HID + ks*32 + hi*8);
    }
    #pragma unroll
    for (int ks = 0; ks < 2; ++ks){
        wihR[ks] = ldfrag(w_ih + (size_t)(      g0)*INP + ks*32 + hi*8);
        wihZ[ks] = ldfrag(w_ih + (size_t)(128 + g0)*INP + ks*32 + hi*8);
        wihN[ks] = ldfrag(w_ih + (size_t)(256 + g0)*INP + ks*32 + hi*8);
    }
    {
        const short8 zz = {0,0,0,0,0,0,0,0};
        #pragma unroll
        for (int ks = 0; ks < 4; ++ks){
            if (wid < 4)            fwA[ks] = ldfrag(fc_in_w + (size_t)(wid*16 + r15)*HID + ks*32 + hi*8);
            else if (wid == 4)      fwA[ks] = (r15 < NOUT) ? ldfrag(fc_out_w + (size_t)r15*HID + ks*32 + hi*8) : zz;
            else                    fwA[ks] = zz;
        }
    }

    // ---- per-thread bias vectors, used directly as MFMA C-init ----
    f32x4 bRv, bZv, bNiv, bNhv, fbv;
    #pragma unroll
    for (int q = 0; q < 4; ++q){
        const int g = wid*16 + hi*4 + q;
        bRv[q]  = b_ih[g]       + b_hh[g];
        bZv[q]  = b_ih[128 + g] + b_hh[128 + g];
        bNiv[q] = b_ih[256 + g];
        bNhv[q] = b_hh[256 + g];
        if (wid < 4)       fbv[q] = fc_in_b[wid*16 + hi*4 + q];
        else if (wid == 4) fbv[q] = (hi == 0 && q < NOUT) ? fc_out_b[q] : 0.0f;
        else               fbv[q] = 0.0f;
    }

    // writer u32 index inside a 2048-u16 h tile (fragment-major scatter):
    //  c = wid*16 + hi*4 + q ; ks'=c>>5, kg=(c>>3)&3, j=c&7 -> pairs (q01) are u32-adjacent
    const int wu32 = (wid>>1)*256 + (((wid&1)*2 + (hi>>1))*16 + r15)*4 + (hi&1)*2;

    // ---- h_old f32 registers + fill h buffer 0 + zero x buffer 0 ----
    float hOld[RT][4];
    const int c0 = wid*16 + hi*4;
    #pragma unroll
    for (int rt = 0; rt < RT; ++rt){
        const f32x4 h4 = *(const f32x4*)(hx + (size_t)(row0 + rt*16 + r15)*HID + c0);
        #pragma unroll
        for (int q = 0; q < 4; ++q) hOld[rt][q] = h4[q];
        u32x2 wv; wv[0] = pack2(h4[0], h4[1]); wv[1] = pack2(h4[2], h4[3]);
        *(u32x2*)((u32*)&hL[0][rt*2048] + wu32) = wv;
    }
    {
        u32* xb = (u32*)&xL[0][0];
        for (int i = tid; i < RT*512; i += NTH) xb[i] = 0u;   // x0 = zeros
    }
    __syncthreads();

    // ---- span head (wave 5): softmax(hx @ span_w.T + b), from day-0 h buffer ----
    if (wid == 5){
        const short8 zz = {0,0,0,0,0,0,0,0};
        short8 spw[4];
        #pragma unroll
        for (int ks = 0; ks < 4; ++ks)
            spw[ks] = (r15 < SPANN) ? ldfrag(span_w + (size_t)r15*HID + ks*32 + hi*8) : zz;
        f32x4 sb = {0.0f, 0.0f, 0.0f, 0.0f};
        #pragma unroll
        for (int q = 0; q < 4; ++q) if (hi < 2) sb[q] = span_b[hi*4 + q];
        #pragma unroll
        for (int rt = 0; rt < RT; ++rt){
            const short8* hf = (const short8*)&hL[0][rt*2048];
            f32x4 acc = sb;
            #pragma unroll
            for (int ks = 0; ks < 4; ++ks) acc = MFMA(spw[ks], hf[ks*64 + l], acc);
            if (hi < 2){   // lanes 0..31 hold spans hi*4+q for row r15
                float m = fmaxf(fmaxf(acc[0], acc[1]), fmaxf(acc[2], acc[3]));
                m = fmaxf(m, __shfl_xor(m, 16));
                float e0 = EXP2F(LOG2E*(acc[0]-m)), e1 = EXP2F(LOG2E*(acc[1]-m));
                float e2 = EXP2F(LOG2E*(acc[2]-m)), e3 = EXP2F(LOG2E*(acc[3]-m));
                float s = e0 + e1 + e2 + e3;
                s += __shfl_xor(s, 16);
                const float inv = RCPF(s);
                f32x4 o = {e0*inv, e1*inv, e2*inv, e3*inv};
                *(f32x4*)(out + (size_t)(row0 + rt*16 + r15)*SPANN + hi*4) = o;
            }
        }
    }

    float* __restrict__ outp = out + (size_t)bs * SPANN;

    #pragma unroll 2
    for (int day = 0; day < DAYS; ++day){
        const int p = day & 1;
        const u16* hRd = hL[p];
        const u16* xRd = xL[p];
        u32* hWr = (u32*)hL[p^1];
        u32* xWr = (u32*)xL[p^1];

        // ============ Phase A: gates + h update (all 8 waves) ============
        #pragma unroll
        for (int rt = 0; rt < RT; ++rt){
            const short8* hf = (const short8*)(hRd + rt*2048);
            const short8* xf = (const short8*)(xRd + rt*1024);
            const short8 h0 = hf[l], h1 = hf[64+l], h2 = hf[128+l], h3 = hf[192+l];
            const short8 x0 = xf[l], x1 = xf[64+l];

            f32x4 aR  = MFMA(whhR[0], h0, bRv);
            f32x4 aZ  = MFMA(whhZ[0], h0, bZv);
            f32x4 aNh = MFMA(whhN[0], h0, bNhv);
            aR  = MFMA(whhR[1], h1, aR);  aZ  = MFMA(whhZ[1], h1, aZ);  aNh = MFMA(whhN[1], h1, aNh);
            aR  = MFMA(whhR[2], h2, aR);  aZ  = MFMA(whhZ[2], h2, aZ);  aNh = MFMA(whhN[2], h2, aNh);
            aR  = MFMA(whhR[3], h3, aR);  aZ  = MFMA(whhZ[3], h3, aZ);  aNh = MFMA(whhN[3], h3, aNh);
            f32x4 aNi = MFMA(wihN[0], x0, bNiv);
            aR  = MFMA(wihR[0], x0, aR);  aZ  = MFMA(wihZ[0], x0, aZ);
            aNi = MFMA(wihN[1], x1, aNi);
            aR  = MFMA(wihR[1], x1, aR);  aZ  = MFMA(wihZ[1], x1, aZ);

            float hn[4];
            #pragma unroll
            for (int q = 0; q < 4; ++q){
                const float rg = sigf(aR[q]);
                const float zg = sigf(aZ[q]);
                const float nn = tanhf_(fmaf(rg, aNh[q], aNi[q]));
                hn[q] = fmaf(zg, hOld[rt][q] - nn, nn);
                hOld[rt][q] = hn[q];
            }
            u32x2 wv; wv[0] = pack2(hn[0], hn[1]); wv[1] = pack2(hn[2], hn[3]);
            *(u32x2*)(hWr + rt*1024 + wu32) = wv;
        }
        __syncthreads();

        // ============ Phase B: fc_in (waves 0-3), fc_out+softmax (wave 4) ============
        if (wid < 4){
            #pragma unroll
            for (int rt = 0; rt < RT; ++rt){
                const short8* hf = (const short8*)(hL[p^1] + rt*2048);
                const short8 h0 = hf[l], h1 = hf[64+l], h2 = hf[128+l], h3 = hf[192+l];
                f32x4 ax = MFMA(fwA[0], h0, fbv);
                ax = MFMA(fwA[1], h1, ax);
                ax = MFMA(fwA[2], h2, ax);
                ax = MFMA(fwA[3], h3, ax);
                u32x2 wv;
                wv[0] = pack2(fmaxf(ax[0],0.0f), fmaxf(ax[1],0.0f));
                wv[1] = pack2(fmaxf(ax[2],0.0f), fmaxf(ax[3],0.0f));
                *(u32x2*)(xWr + rt*512 + wu32) = wv;
            }
        } else if (wid == 4){
            #pragma unroll
            for (int rt = 0; rt < RT; ++rt){
                const short8* hf = (const short8*)(hL[p^1] + rt*2048);
                const short8 h0 = hf[l], h1 = hf[64+l], h2 = hf[128+l], h3 = hf[192+l];
                f32x4 ao = MFMA(fwA[0], h0, fbv);
                ao = MFMA(fwA[1], h1, ao);
                ao = MFMA(fwA[2], h2, ao);
                ao = MFMA(fwA[3], h3, ao);
                if (hi == 0){   // lanes 0..15 hold both logits (q=0,1) for row r15
                    const float m  = fmaxf(ao[0], ao[1]);
                    const float e0 = EXP2F(LOG2E*(ao[0]-m));
                    const float e1 = EXP2F(LOG2E*(ao[1]-m));
                    const float inv = RCPF(e0 + e1);
                    f32x2 o = {e0*inv, e1*inv};
                    *(f32x2*)(outp + ((size_t)(row0 + rt*16 + r15)*DAYS + day)*NOUT) = o;
                }
            }
        }
        __syncthreads();
    }
}

extern "C" void kernel_launch(void* const* d_in, const int* in_sizes, int n_in,
                              void* d_out, int out_size, void* d_ws, size_t ws_size,
                              hipStream_t stream) {
    const float* hx       = (const float*)d_in[0];
    const float* w_ih     = (const float*)d_in[1];
    const float* w_hh     = (const float*)d_in[2];
    const float* b_ih     = (const float*)d_in[3];
    const float* b_hh     = (const float*)d_in[4];
    const float* fc_in_w  = (const float*)d_in[5];
    const float* fc_in_b  = (const float*)d_in[6];
    const float* fc_out_w = (const float*)d_in[7];
    const float* fc_out_b = (const float*)d_in[8];
    const float* span_w   = (const float*)d_in[9];
    const float* span_b   = (const float*)d_in[10];
    float* out = (float*)d_out;

    const int bs = in_sizes[0] / HID;            // 32768
    dim3 grid(bs / ROWS), block(NTH);
    gru_mfma<<<grid, block, 0, stream>>>(hx, w_ih, w_hh, b_ih, b_hh,
                                         fc_in_w, fc_in_b, fc_out_w, fc_out_b,
                                         span_w, span_b, out, bs);
}

// Round 5
// 143.858 us; speedup vs baseline: 3.6433x; 1.0406x over previous
//
#include <hip/hip_runtime.h>
#include <hip/hip_bf16.h>

#define HID 128
#define INP 64
#define SPANN 8
#define NOUT 2
#define DAYS 20
#define RT 4                 // 16-row tiles per block
#define ROWS (16*RT)         // 64 batch rows per block
#define NTH 512              // 8 waves

typedef __attribute__((ext_vector_type(8))) short short8;
typedef __attribute__((ext_vector_type(4))) float f32x4;
typedef __attribute__((ext_vector_type(2))) float f32x2;
typedef unsigned int u32;
typedef __attribute__((ext_vector_type(2))) u32 u32x2;
typedef unsigned short u16;

#define MFMA(a,b,c) __builtin_amdgcn_mfma_f32_16x16x32_bf16(a,b,c,0,0,0)
#define RCPF(x)  __builtin_amdgcn_rcpf(x)
#define EXP2F(x) __builtin_amdgcn_exp2f(x)
#define LOG2E  1.4426950408889634f
#define LOG2E2 2.8853900817779268f

__device__ __forceinline__ u32 pack2(float a, float b){
    __hip_bfloat162 h = __float22bfloat162_rn(float2{a, b});
    u32 r; __builtin_memcpy(&r, &h, 4); return r;
}
__device__ __forceinline__ float sigf(float x){ return RCPF(1.0f + EXP2F(-LOG2E * x)); }
__device__ __forceinline__ float tanhf_(float x){ return fmaf(-2.0f, RCPF(1.0f + EXP2F(LOG2E2 * x)), 1.0f); }

union frag_u { short8 s; u32 w[4]; };
__device__ __forceinline__ short8 ldfrag(const float* p){
    const f32x4 a = *(const f32x4*)p;
    const f32x4 b = *(const f32x4*)(p+4);
    frag_u f;
    f.w[0] = pack2(a[0],a[1]); f.w[1] = pack2(a[2],a[3]);
    f.w[2] = pack2(b[0],b[1]); f.w[3] = pack2(b[2],b[3]);
    return f.s;
}

// Fragment conventions (16x16x32 bf16):
//  A: lane holds A[m = l&15][k = (l>>4)*8 + j]   (weights)
//  B: lane holds B[k = (l>>4)*8 + j][n = l&15]   (h^T / x^T, n = batch row)
//  D: lane holds D[m = (l>>4)*4 + q][n = l&15]   (m89-verified)
// h/x LDS tiles are fragment-major: k-step ks at ks*1024B + l*16B.

// min-waves/EU=2 (NOT 4): R3 showed =4 caps VGPR at 128 and spills the
// resident weight fragments -> 1.35 GB scratch traffic. Keep 2.
__global__ __launch_bounds__(NTH, 2) void gru_mfma(
    const float* __restrict__ hx, const float* __restrict__ w_ih,
    const float* __restrict__ w_hh, const float* __restrict__ b_ih,
    const float* __restrict__ b_hh, const float* __restrict__ fc_in_w,
    const float* __restrict__ fc_in_b, const float* __restrict__ fc_out_w,
    const float* __restrict__ fc_out_b, const float* __restrict__ span_w,
    const float* __restrict__ span_b, float* __restrict__ out, int bs)
{
    __shared__ u16 hL[2][RT*2048];                       // 32 KiB, day-parity dbuf
    __shared__ u16 xL[RT*1024];                          // 8 KiB, single buffer
    __shared__ u16 finL[4*4*64*8];                       // 16 KiB fc_in_w A-frags
    __shared__ __attribute__((aligned(16))) float diffP[ROWS][8];  // 2 KiB fc_out partials

    const int tid = threadIdx.x;
    const int wid = tid >> 6;        // 0..7, owns gate m-tiles {wid, wid+8, wid+16}
    const int l   = tid & 63;
    const int r15 = l & 15;
    const int hi  = l >> 4;
    const int row0 = blockIdx.x * ROWS;
    const int mB  = wid & 3;         // fc_in m-tile for Phase B
    const int rtB_off = wid >> 2;    // fc_in row-tile offset (0/1)

    // ---- resident weight fragments (gates only now) ----
    short8 whhR[4], whhZ[4], whhN[4];
    short8 wihR[2], wihZ[2], wihN[2];
    const int g0 = wid*16 + r15;
    #pragma unroll
    for (int ks = 0; ks < 4; ++ks){
        whhR[ks] = ldfrag(w_hh + (size_t)(      g0)*HID + ks*32 + hi*8);
        whhZ[ks] = ldfrag(w_hh + (size_t)(128 + g0)*HID + ks*32 + hi*8);
        whhN[ks] = ldfrag(w_hh + (size_t)(256 + g0)*HID + ks*32 + hi*8);
    }
    #pragma unroll
    for (int ks = 0; ks < 2; ++ks){
        wihR[ks] = ldfrag(w_ih + (size_t)(      g0)*INP + ks*32 + hi*8);
        wihZ[ks] = ldfrag(w_ih + (size_t)(128 + g0)*INP + ks*32 + hi*8);
        wihN[ks] = ldfrag(w_ih + (size_t)(256 + g0)*INP + ks*32 + hi*8);
    }

    // ---- stage fc_in_w into LDS as A-fragments (one copy for all waves) ----
    for (int s = tid; s < 1024; s += NTH) {
        const int mt = s >> 8, ks = (s >> 6) & 3, ll = s & 63;
        short8 f = ldfrag(fc_in_w + (size_t)(mt*16 + (ll&15))*HID + ks*32 + (ll>>4)*8);
        *((short8*)finL + s) = f;
    }

    // ---- biases / fc_out diff weights ----
    f32x4 bRv, bZv, bNiv, bNhv, fbv, wd4;
    const int c0 = wid*16 + hi*4;
    #pragma unroll
    for (int q = 0; q < 4; ++q){
        const int g = c0 + q;
        bRv[q]  = b_ih[g]       + b_hh[g];
        bZv[q]  = b_ih[128 + g] + b_hh[128 + g];
        bNiv[q] = b_ih[256 + g];
        bNhv[q] = b_hh[256 + g];
        fbv[q]  = fc_in_b[mB*16 + hi*4 + q];
        wd4[q]  = fc_out_w[g] - fc_out_w[HID + g];       // w0 - w1 slice
    }
    const float bd = fc_out_b[0] - fc_out_b[1];          // uniform -> SGPR

    // scatter index (u32 units) of this thread's 4 output cols in a frag-major tile
    const int wu32  = (wid>>1)*256 + (((wid&1)*2 + (hi>>1))*16 + r15)*4 + (hi&1)*2;
    const int xwu32 = (mB >>1)*256 + (((mB &1)*2 + (hi>>1))*16 + r15)*4 + (hi&1)*2;

    // ---- h_old f32 regs + fill hL[0] + zero xL ----
    f32x4 hOld0, hOld1, hOld2, hOld3;
    {
        #define LOADH(RTG, HO) do { \
            const f32x4 h4 = *(const f32x4*)(hx + (size_t)(row0 + (RTG)*16 + r15)*HID + c0); \
            HO = h4; \
            u32x2 wv; wv[0] = pack2(h4[0], h4[1]); wv[1] = pack2(h4[2], h4[3]); \
            *(u32x2*)((u32*)&hL[0][(RTG)*2048] + wu32) = wv; } while(0)
        LOADH(0, hOld0); LOADH(1, hOld1); LOADH(2, hOld2); LOADH(3, hOld3);
        #undef LOADH
        u32* xb = (u32*)&xL[0];
        for (int i = tid; i < RT*512; i += NTH) xb[i] = 0u;
    }
    __syncthreads();

    // ---- span head: waves 0-3, one row-tile each (reads hL[0], writes global) ----
    if (wid < 4){
        const short8 zz = {0,0,0,0,0,0,0,0};
        short8 spw[4];
        #pragma unroll
        for (int ks = 0; ks < 4; ++ks)
            spw[ks] = (r15 < SPANN) ? ldfrag(span_w + (size_t)r15*HID + ks*32 + hi*8) : zz;
        f32x4 acc = {0.f,0.f,0.f,0.f};
        #pragma unroll
        for (int q = 0; q < 4; ++q) if (hi < 2) acc[q] = span_b[hi*4 + q];
        const short8* hf = (const short8*)&hL[0][wid*2048];
        #pragma unroll
        for (int ks = 0; ks < 4; ++ks) acc = MFMA(spw[ks], hf[ks*64 + l], acc);
        if (hi < 2){
            float m = fmaxf(fmaxf(acc[0], acc[1]), fmaxf(acc[2], acc[3]));
            m = fmaxf(m, __shfl_xor(m, 16));
            float e0 = EXP2F(LOG2E*(acc[0]-m)), e1 = EXP2F(LOG2E*(acc[1]-m));
            float e2 = EXP2F(LOG2E*(acc[2]-m)), e3 = EXP2F(LOG2E*(acc[3]-m));
            float s = e0 + e1 + e2 + e3;
            s += __shfl_xor(s, 16);
            const float inv = RCPF(s);
            f32x4 o = {e0*inv, e1*inv, e2*inv, e3*inv};
            *(f32x4*)(out + (size_t)(row0 + wid*16 + r15)*SPANN + hi*4) = o;
        }
    }

    float* __restrict__ outp = out + (size_t)bs * SPANN;

    // ---- macros: one gate tile (A), one fc_in unit + out-store (B) ----
    #define TILE_A(RTG, hRd_, hWr_, HO) do { \
        const short8* hf = (const short8*)((hRd_) + (RTG)*2048); \
        const short8* xf = (const short8*)(xL + (RTG)*1024); \
        const short8 h0=hf[l], h1=hf[64+l], h2=hf[128+l], h3=hf[192+l]; \
        const short8 x0=xf[l], x1=xf[64+l]; \
        f32x4 aR  = MFMA(whhR[0], h0, bRv); \
        f32x4 aZ  = MFMA(whhZ[0], h0, bZv); \
        f32x4 aNh = MFMA(whhN[0], h0, bNhv); \
        aR = MFMA(whhR[1],h1,aR); aZ = MFMA(whhZ[1],h1,aZ); aNh = MFMA(whhN[1],h1,aNh); \
        aR = MFMA(whhR[2],h2,aR); aZ = MFMA(whhZ[2],h2,aZ); aNh = MFMA(whhN[2],h2,aNh); \
        aR = MFMA(whhR[3],h3,aR); aZ = MFMA(whhZ[3],h3,aZ); aNh = MFMA(whhN[3],h3,aNh); \
        f32x4 aNi = MFMA(wihN[0], x0, bNiv); \
        aR = MFMA(wihR[0],x0,aR); aZ = MFMA(wihZ[0],x0,aZ); \
        aNi = MFMA(wihN[1],x1,aNi); \
        aR = MFMA(wihR[1],x1,aR); aZ = MFMA(wihZ[1],x1,aZ); \
        float hn[4]; \
        _Pragma("unroll") for (int q=0;q<4;++q){ \
            const float rg = sigf(aR[q]); const float zg = sigf(aZ[q]); \
            const float nn = tanhf_(fmaf(rg, aNh[q], aNi[q])); \
            hn[q] = fmaf(zg, HO[q]-nn, nn); HO[q] = hn[q]; } \
        u32x2 wv; wv[0]=pack2(hn[0],hn[1]); wv[1]=pack2(hn[2],hn[3]); \
        *(u32x2*)((hWr_) + (RTG)*1024 + wu32) = wv; \
        float pd = hn[0]*wd4[0]; pd = fmaf(hn[1],wd4[1],pd); \
        pd = fmaf(hn[2],wd4[2],pd); pd = fmaf(hn[3],wd4[3],pd); \
        pd += __shfl_xor(pd, 16); pd += __shfl_xor(pd, 32); \
        if (hi == 0) diffP[(RTG)*16 + r15][wid] = pd; \
    } while(0)

    #define OUT_STORE(d_, gb_) do { \
        if (wid == 7 && l < 32) { \
            const int rowIdx = (gb_)*32 + l; \
            const f32x4 v0 = *(const f32x4*)&diffP[rowIdx][0]; \
            const f32x4 v1 = *(const f32x4*)&diffP[rowIdx][4]; \
            const float s = ((v0[0]+v0[1])+(v0[2]+v0[3])) + ((v1[0]+v1[1])+(v1[2]+v1[3])); \
            const float p0 = sigf(s + bd); \
            f32x2 o = {p0, 1.0f - p0}; \
            *(f32x2*)(outp + ((size_t)(row0 + rowIdx)*DAYS + (d_))*NOUT) = o; \
        } \
    } while(0)

    #define TILE_B(d_, gb_, hSrc) do { \
        if ((d_) < DAYS-1) { \
            const int rtB = 2*(gb_) + rtB_off; \
            const short8* hf = (const short8*)((hSrc) + rtB*2048); \
            const short8 h0=hf[l], h1=hf[64+l], h2=hf[128+l], h3=hf[192+l]; \
            const short8* fp = (const short8*)finL + mB*256 + l; \
            f32x4 ax = MFMA(fp[0],   h0, fbv); \
            ax       = MFMA(fp[64],  h1, ax); \
            ax       = MFMA(fp[128], h2, ax); \
            ax       = MFMA(fp[192], h3, ax); \
            u32x2 wv; \
            wv[0] = pack2(fmaxf(ax[0],0.f), fmaxf(ax[1],0.f)); \
            wv[1] = pack2(fmaxf(ax[2],0.f), fmaxf(ax[3],0.f)); \
            *(u32x2*)((u32*)xL + rtB*512 + xwu32) = wv; \
        } \
        OUT_STORE(d_, gb_); \
    } while(0)

    // ---- day loop: two super-phases, A(Gx) overlapped with B(Gy) ----
    #pragma unroll 2
    for (int d = 0; d < DAYS; ++d){
        const u16* hRd = hL[d & 1];
        u32*       hWr = (u32*)hL[(d & 1) ^ 1];

        // SP even: A(G0, d)  ||  B(G1, d-1) + out(G1, d-1)
        TILE_A(0, hRd, hWr, hOld0);
        TILE_A(1, hRd, hWr, hOld1);
        if (d > 0) TILE_B(d-1, 1, hRd);
        __syncthreads();

        // SP odd:  A(G1, d)  ||  B(G0, d) + out(G0, d)
        TILE_A(2, hRd, hWr, hOld2);
        TILE_A(3, hRd, hWr, hOld3);
        TILE_B(d, 0, (const u16*)hWr);
        __syncthreads();
    }
    // epilogue: out(G1, last day)
    OUT_STORE(DAYS-1, 1);

    #undef TILE_A
    #undef TILE_B
    #undef OUT_STORE
}

extern "C" void kernel_launch(void* const* d_in, const int* in_sizes, int n_in,
                              void* d_out, int out_size, void* d_ws, size_t ws_size,
                              hipStream_t stream) {
    const float* hx       = (const float*)d_in[0];
    const float* w_ih     = (const float*)d_in[1];
    const float* w_hh     = (const float*)d_in[2];
    const float* b_ih     = (const float*)d_in[3];
    const float* b_hh     = (const float*)d_in[4];
    const float* fc_in_w  = (const float*)d_in[5];
    const float* fc_in_b  = (const float*)d_in[6];
    const float* fc_out_w = (const float*)d_in[7];
    const float* fc_out_b = (const float*)d_in[8];
    const float* span_w   = (const float*)d_in[9];
    const float* span_b   = (const float*)d_in[10];
    float* out = (float*)d_out;

    const int bs = in_sizes[0] / HID;            // 32768
    dim3 grid(bs / ROWS), block(NTH);
    gru_mfma<<<grid, block, 0, stream>>>(hx, w_ih, w_hh, b_ih, b_hh,
                                         fc_in_w, fc_in_b, fc_out_w, fc_out_b,
                                         span_w, span_b, out, bs);
}

// Round 6
// 143.667 us; speedup vs baseline: 3.6482x; 1.0013x over previous
//
#include <hip/hip_runtime.h>
#include <hip/hip_bf16.h>

#define HID 128
#define INP 64
#define SPANN 8
#define NOUT 2
#define DAYS 20
#define RT 4                 // 16-row tiles per block
#define ROWS (16*RT)         // 64 batch rows per block
#define NTH 512              // 8 waves

typedef __attribute__((ext_vector_type(8))) short short8;
typedef __attribute__((ext_vector_type(4))) float f32x4;
typedef __attribute__((ext_vector_type(2))) float f32x2;
typedef unsigned int u32;
typedef __attribute__((ext_vector_type(2))) u32 u32x2;
typedef unsigned short u16;

#define MFMA(a,b,c) __builtin_amdgcn_mfma_f32_16x16x32_bf16(a,b,c,0,0,0)
#define RCPF(x)  __builtin_amdgcn_rcpf(x)
#define EXP2F(x) __builtin_amdgcn_exp2f(x)
#define LOG2E   1.4426950408889634f
#define NLOG2E  (-1.4426950408889634f)
#define LOG2E2  2.8853900817779268f

__device__ __forceinline__ u32 pack2(float a, float b){
    __hip_bfloat162 h = __float22bfloat162_rn(float2{a, b});
    u32 r; __builtin_memcpy(&r, &h, 4); return r;
}
__device__ __forceinline__ float asF(u32 u){ union{u32 u; float f;} v; v.u = u; return v.f; }
// pre-scaled activations: arg already multiplied by -log2e (sig) / 2log2e (tanh)
__device__ __forceinline__ float sig2(float a){ return RCPF(1.0f + EXP2F(a)); }
__device__ __forceinline__ float tanh2(float a){ return fmaf(-2.0f, RCPF(1.0f + EXP2F(a)), 1.0f); }

union frag_u { short8 s; u32 w[4]; };
// load 8 consecutive f32, scale, convert to a bf16 MFMA fragment (4 VGPRs)
__device__ __forceinline__ short8 ldfrag(const float* p, float sc){
    const f32x4 a = *(const f32x4*)p;
    const f32x4 b = *(const f32x4*)(p+4);
    frag_u f;
    f.w[0] = pack2(sc*a[0],sc*a[1]); f.w[1] = pack2(sc*a[2],sc*a[3]);
    f.w[2] = pack2(sc*b[0],sc*b[1]); f.w[3] = pack2(sc*b[2],sc*b[3]);
    return f.s;
}

// Fragment conventions (16x16x32 bf16):
//  A: lane holds A[m = l&15][k = (l>>4)*8 + j]   (weights)
//  B: lane holds B[k = (l>>4)*8 + j][n = l&15]   (h^T / x^T, n = batch row)
//  D: lane holds D[m = (l>>4)*4 + q][n = l&15]   (m89-verified)
// h/x LDS tiles are fragment-major: k-step ks at ks*1024B + l*16B.
// R/Z (and fc_out-diff) weights+biases pre-scaled by -log2e, N by 2log2e:
// MFMA emits activation args directly in exp2 domain (saves 3 v_mul/elem).

// min-waves/EU=2 (NOT 4): R3 showed =4 caps VGPR at 128 and spills the
// resident weight fragments -> 1.35 GB scratch traffic. Keep 2.
__global__ __launch_bounds__(NTH, 2) void gru_mfma(
    const float* __restrict__ hx, const float* __restrict__ w_ih,
    const float* __restrict__ w_hh, const float* __restrict__ b_ih,
    const float* __restrict__ b_hh, const float* __restrict__ fc_in_w,
    const float* __restrict__ fc_in_b, const float* __restrict__ fc_out_w,
    const float* __restrict__ fc_out_b, const float* __restrict__ span_w,
    const float* __restrict__ span_b, float* __restrict__ out, int bs)
{
    __shared__ u16 hL[2][RT*2048];                       // 32 KiB, day-parity dbuf
    __shared__ u16 xL[RT*1024];                          // 8 KiB, single buffer
    __shared__ u16 finL[4*4*64*8];                       // 16 KiB fc_in_w A-frags
    __shared__ float diffP[ROWS][9];                     // fc_out partials, stride 9

    const int tid = threadIdx.x;
    const int wid = tid >> 6;        // 0..7, owns gate m-tiles {wid, wid+8, wid+16}
    const int l   = tid & 63;
    const int r15 = l & 15;
    const int hi  = l >> 4;
    const int row0 = blockIdx.x * ROWS;
    const int mB  = wid & 3;         // fc_in m-tile for Phase B
    const int rtB_off = wid >> 2;    // fc_in row-tile offset (0/1)

    // ---- resident weight fragments (gates only), pre-scaled ----
    short8 whhR[4], whhZ[4], whhN[4];
    short8 wihR[2], wihZ[2], wihN[2];
    const int g0 = wid*16 + r15;
    #pragma unroll
    for (int ks = 0; ks < 4; ++ks){
        whhR[ks] = ldfrag(w_hh + (size_t)(      g0)*HID + ks*32 + hi*8, NLOG2E);
        whhZ[ks] = ldfrag(w_hh + (size_t)(128 + g0)*HID + ks*32 + hi*8, NLOG2E);
        whhN[ks] = ldfrag(w_hh + (size_t)(256 + g0)*HID + ks*32 + hi*8, LOG2E2);
    }
    #pragma unroll
    for (int ks = 0; ks < 2; ++ks){
        wihR[ks] = ldfrag(w_ih + (size_t)(      g0)*INP + ks*32 + hi*8, NLOG2E);
        wihZ[ks] = ldfrag(w_ih + (size_t)(128 + g0)*INP + ks*32 + hi*8, NLOG2E);
        wihN[ks] = ldfrag(w_ih + (size_t)(256 + g0)*INP + ks*32 + hi*8, LOG2E2);
    }

    // ---- stage fc_in_w into LDS as A-fragments (one copy for all waves) ----
    for (int s = tid; s < 1024; s += NTH) {
        const int mt = s >> 8, ks = (s >> 6) & 3, ll = s & 63;
        short8 f = ldfrag(fc_in_w + (size_t)(mt*16 + (ll&15))*HID + ks*32 + (ll>>4)*8, 1.0f);
        *((short8*)finL + s) = f;
    }

    // ---- biases (pre-scaled) / fc_out diff weights (pre-scaled) ----
    f32x4 bRv, bZv, bNiv, bNhv, fbv, wd4;
    const int c0 = wid*16 + hi*4;
    #pragma unroll
    for (int q = 0; q < 4; ++q){
        const int g = c0 + q;
        bRv[q]  = NLOG2E*(b_ih[g]       + b_hh[g]);
        bZv[q]  = NLOG2E*(b_ih[128 + g] + b_hh[128 + g]);
        bNiv[q] = LOG2E2* b_ih[256 + g];
        bNhv[q] = LOG2E2* b_hh[256 + g];
        fbv[q]  = fc_in_b[mB*16 + hi*4 + q];
        wd4[q]  = NLOG2E*(fc_out_w[g] - fc_out_w[HID + g]);
    }
    const float bd = NLOG2E*(fc_out_b[0] - fc_out_b[1]);

    // scatter index (u32 units) of this thread's 4 output cols in a frag-major tile
    const int wu32  = (wid>>1)*256 + (((wid&1)*2 + (hi>>1))*16 + r15)*4 + (hi&1)*2;
    const int xwu32 = (mB >>1)*256 + (((mB &1)*2 + (hi>>1))*16 + r15)*4 + (hi&1)*2;

    // ---- fill hL[0] from hx + zero xL (h state lives ONLY in LDS as bf16) ----
    {
        #pragma unroll
        for (int rt = 0; rt < RT; ++rt){
            const f32x4 h4 = *(const f32x4*)(hx + (size_t)(row0 + rt*16 + r15)*HID + c0);
            u32x2 wv; wv[0] = pack2(h4[0], h4[1]); wv[1] = pack2(h4[2], h4[3]);
            *(u32x2*)((u32*)&hL[0][rt*2048] + wu32) = wv;
        }
        u32* xb = (u32*)&xL[0];
        for (int i = tid; i < RT*512; i += NTH) xb[i] = 0u;
    }
    __syncthreads();

    // ---- span head: waves 0-3, one row-tile each (reads hL[0]) ----
    if (wid < 4){
        const short8 zz = {0,0,0,0,0,0,0,0};
        short8 spw[4];
        #pragma unroll
        for (int ks = 0; ks < 4; ++ks)
            spw[ks] = (r15 < SPANN) ? ldfrag(span_w + (size_t)r15*HID + ks*32 + hi*8, 1.0f) : zz;
        f32x4 acc = {0.f,0.f,0.f,0.f};
        #pragma unroll
        for (int q = 0; q < 4; ++q) if (hi < 2) acc[q] = span_b[hi*4 + q];
        const short8* hf = (const short8*)&hL[0][wid*2048];
        #pragma unroll
        for (int ks = 0; ks < 4; ++ks) acc = MFMA(spw[ks], hf[ks*64 + l], acc);
        if (hi < 2){
            float m = fmaxf(fmaxf(acc[0], acc[1]), fmaxf(acc[2], acc[3]));
            m = fmaxf(m, __shfl_xor(m, 16));
            float e0 = EXP2F(LOG2E*(acc[0]-m)), e1 = EXP2F(LOG2E*(acc[1]-m));
            float e2 = EXP2F(LOG2E*(acc[2]-m)), e3 = EXP2F(LOG2E*(acc[3]-m));
            float s = e0 + e1 + e2 + e3;
            s += __shfl_xor(s, 16);
            const float inv = RCPF(s);
            f32x4 o = {e0*inv, e1*inv, e2*inv, e3*inv};
            *(f32x4*)(out + (size_t)(row0 + wid*16 + r15)*SPANN + hi*4) = o;
        }
    }

    float* __restrict__ outp = out + (size_t)bs * SPANN;

    // ---- macros: one gate tile (A), one fc_in unit + out-store (B) ----
    #define TILE_A(RTG, hRd_, hWr_) do { \
        const short8* hf = (const short8*)((hRd_) + (RTG)*2048); \
        const short8* xf = (const short8*)(xL + (RTG)*1024); \
        const short8 h0=hf[l], h1=hf[64+l], h2=hf[128+l], h3=hf[192+l]; \
        const short8 x0=xf[l], x1=xf[64+l]; \
        const u32x2 ho = *(const u32x2*)((const u32*)(hRd_) + (RTG)*1024 + wu32); \
        f32x4 aR  = MFMA(whhR[0], h0, bRv); \
        f32x4 aZ  = MFMA(whhZ[0], h0, bZv); \
        f32x4 aNh = MFMA(whhN[0], h0, bNhv); \
        aR = MFMA(whhR[1],h1,aR); aZ = MFMA(whhZ[1],h1,aZ); aNh = MFMA(whhN[1],h1,aNh); \
        aR = MFMA(whhR[2],h2,aR); aZ = MFMA(whhZ[2],h2,aZ); aNh = MFMA(whhN[2],h2,aNh); \
        aR = MFMA(whhR[3],h3,aR); aZ = MFMA(whhZ[3],h3,aZ); aNh = MFMA(whhN[3],h3,aNh); \
        f32x4 aNi = MFMA(wihN[0], x0, bNiv); \
        aR = MFMA(wihR[0],x0,aR); aZ = MFMA(wihZ[0],x0,aZ); \
        aNi = MFMA(wihN[1],x1,aNi); \
        aR = MFMA(wihR[1],x1,aR); aZ = MFMA(wihZ[1],x1,aZ); \
        const float hold[4] = { asF(ho[0]<<16), asF(ho[0]&0xFFFF0000u), \
                                asF(ho[1]<<16), asF(ho[1]&0xFFFF0000u) }; \
        float hn[4]; \
        _Pragma("unroll") for (int q=0;q<4;++q){ \
            const float rg = sig2(aR[q]); const float zg = sig2(aZ[q]); \
            const float nn = tanh2(fmaf(rg, aNh[q], aNi[q])); \
            hn[q] = fmaf(zg, hold[q]-nn, nn); } \
        u32x2 wv; wv[0]=pack2(hn[0],hn[1]); wv[1]=pack2(hn[2],hn[3]); \
        *(u32x2*)((hWr_) + (RTG)*1024 + wu32) = wv; \
        float pd = hn[0]*wd4[0]; pd = fmaf(hn[1],wd4[1],pd); \
        pd = fmaf(hn[2],wd4[2],pd); pd = fmaf(hn[3],wd4[3],pd); \
        pd += __shfl_xor(pd, 16); pd += __shfl_xor(pd, 32); \
        if (hi == 0) diffP[(RTG)*16 + r15][wid] = pd; \
    } while(0)

    #define OUT_STORE(d_, gb_) do { \
        if (wid == 7 && l < 32) { \
            const int rowIdx = (gb_)*32 + l; \
            const float* dp = &diffP[rowIdx][0]; \
            const float s = ((dp[0]+dp[1])+(dp[2]+dp[3])) + ((dp[4]+dp[5])+(dp[6]+dp[7])); \
            const float p0 = sig2(s + bd); \
            f32x2 o = {p0, 1.0f - p0}; \
            *(f32x2*)(outp + ((size_t)(row0 + rowIdx)*DAYS + (d_))*NOUT) = o; \
        } \
    } while(0)

    #define TILE_B(d_, gb_, hSrc) do { \
        if ((d_) < DAYS-1) { \
            const int rtB = 2*(gb_) + rtB_off; \
            const short8* hf = (const short8*)((hSrc) + rtB*2048); \
            const short8 h0=hf[l], h1=hf[64+l], h2=hf[128+l], h3=hf[192+l]; \
            const short8* fp = (const short8*)finL + mB*256 + l; \
            f32x4 ax = MFMA(fp[0],   h0, fbv); \
            ax       = MFMA(fp[64],  h1, ax); \
            ax       = MFMA(fp[128], h2, ax); \
            ax       = MFMA(fp[192], h3, ax); \
            u32x2 wv; \
            wv[0] = pack2(fmaxf(ax[0],0.f), fmaxf(ax[1],0.f)); \
            wv[1] = pack2(fmaxf(ax[2],0.f), fmaxf(ax[3],0.f)); \
            *(u32x2*)((u32*)xL + rtB*512 + xwu32) = wv; \
        } \
        OUT_STORE(d_, gb_); \
    } while(0)

    // ---- day loop: two super-phases, A(Gx) overlapped with B(Gy) ----
    #pragma unroll 1
    for (int d = 0; d < DAYS; ++d){
        const u16* hRd = hL[d & 1];
        u32*       hWr = (u32*)hL[(d & 1) ^ 1];

        // SP even: A(G0, d)  ||  B(G1, d-1) + out(G1, d-1)
        TILE_A(0, hRd, hWr);
        TILE_A(1, hRd, hWr);
        if (d > 0) TILE_B(d-1, 1, hRd);
        __syncthreads();

        // SP odd:  A(G1, d)  ||  B(G0, d) + out(G0, d)
        TILE_A(2, hRd, hWr);
        TILE_A(3, hRd, hWr);
        TILE_B(d, 0, (const u16*)hWr);
        __syncthreads();
    }
    // epilogue: out(G1, last day)
    OUT_STORE(DAYS-1, 1);

    #undef TILE_A
    #undef TILE_B
    #undef OUT_STORE
}

extern "C" void kernel_launch(void* const* d_in, const int* in_sizes, int n_in,
                              void* d_out, int out_size, void* d_ws, size_t ws_size,
                              hipStream_t stream) {
    const float* hx       = (const float*)d_in[0];
    const float* w_ih     = (const float*)d_in[1];
    const float* w_hh     = (const float*)d_in[2];
    const float* b_ih     = (const float*)d_in[3];
    const float* b_hh     = (const float*)d_in[4];
    const float* fc_in_w  = (const float*)d_in[5];
    const float* fc_in_b  = (const float*)d_in[6];
    const float* fc_out_w = (const float*)d_in[7];
    const float* fc_out_b = (const float*)d_in[8];
    const float* span_w   = (const float*)d_in[9];
    const float* span_b   = (const float*)d_in[10];
    float* out = (float*)d_out;

    const int bs = in_sizes[0] / HID;            // 32768
    dim3 grid(bs / ROWS), block(NTH);
    gru_mfma<<<grid, block, 0, stream>>>(hx, w_ih, w_hh, b_ih, b_hh,
                                         fc_in_w, fc_in_b, fc_out_w, fc_out_b,
                                         span_w, span_b, out, bs);
}